// Round 3
// baseline (701.939 us; speedup 1.0000x reference)
//
#include <hip/hip_runtime.h>
#include <hip/hip_bf16.h>

#define NN 50000
#define EE 600000
#define HH 128
#define CC 40
#define NEG 0.1f

typedef __attribute__((ext_vector_type(8))) short bf16x8;
typedef __attribute__((ext_vector_type(4))) float f32x4;

__device__ __forceinline__ unsigned short f2bf(float f) {
    unsigned u = __float_as_uint(f);
    unsigned r = u + 0x7fffu + ((u >> 16) & 1u);
    return (unsigned short)(r >> 16);
}
__device__ __forceinline__ float bfhi(unsigned v) {  // high bf16 of packed dword
    return __uint_as_float(v & 0xFFFF0000u);
}
__device__ __forceinline__ float bflo(unsigned v) {  // low bf16
    return __uint_as_float(v << 16);
}

// ---------------- CSR build ----------------

__global__ void k_count(const int* __restrict__ dst, int* __restrict__ counts) {
    int e = blockIdx.x * blockDim.x + threadIdx.x;
    if (e < EE) {
        int d = dst[e];
        if ((unsigned)d < (unsigned)NN) atomicAdd(&counts[d], 1);
    }
}

// simple 3-phase single-block scan: 1024 threads, chunk = 49 (1024*49 >= NN)
__global__ void k_scan2(const int* __restrict__ counts, int* __restrict__ offsets,
                        int* __restrict__ cursor, float* __restrict__ inv) {
    __shared__ int part[1024];
    __shared__ int wtot[16];
    __shared__ int wex[16];
    const int CH = 49;
    int t = threadIdx.x;
    int lo = t * CH;
    int hi = lo + CH; if (hi > NN) hi = NN;
    int s = 0;
    for (int i = lo; i < hi; ++i) s += counts[i];
    part[t] = s;
    __syncthreads();
    if (t < 16) {  // sequential exclusive scan of one 64-chunk group
        int run = 0;
        for (int j = 0; j < 64; ++j) {
            int v = part[t * 64 + j];
            part[t * 64 + j] = run;
            run += v;
        }
        wtot[t] = run;
    }
    __syncthreads();
    if (t == 0) {
        int run = 0;
        for (int w = 0; w < 16; ++w) { wex[w] = run; run += wtot[w]; }
        offsets[NN] = run;
    }
    __syncthreads();
    int run = wex[t >> 6] + part[t];
    for (int i = lo; i < hi; ++i) {
        int c = counts[i];
        offsets[i] = run;
        cursor[i]  = run;
        inv[i] = (c > 0) ? 1.0f / (float)c : 1.0f;
        run += c;
    }
}

__global__ void k_scatter(const int* __restrict__ src, const int* __restrict__ dst,
                          int* __restrict__ cursor, int* __restrict__ csr) {
    int e = blockIdx.x * blockDim.x + threadIdx.x;
    if (e < EE) {
        int d = dst[e];
        if ((unsigned)d < (unsigned)NN) {
            int pos = atomicAdd(&cursor[d], 1);
            csr[pos] = src[e];
        }
    }
}

// ---------------- weight swizzle (fp32 -> bf16 B-fragment order) ----------------
// B-frag for 16x16x32: lane l holds B[k = kt*32 + (l>>4)*8 + j][n = t*16 + (l&15)]
__global__ void k_swz(const float* __restrict__ W, unsigned short* __restrict__ dstf,
                      int dout, int doutp) {
    int idx = blockIdx.x * blockDim.x + threadIdx.x;
    int tot = HH * doutp;
    if (idx >= tot) return;
    int k = idx / doutp, n = idx % doutp;
    unsigned short val = (n < dout) ? f2bf(W[k * dout + n]) : (unsigned short)0;
    int kt = k >> 5, kin = k & 31, nt = n >> 4, nin = n & 15;
    int lane = ((kin >> 3) << 4) | nin;
    int j = kin & 7;
    int NT = doutp >> 4;
    dstf[(((kt * NT + nt) * 64) + lane) * 8 + j] = val;
}

// ---------------- fused aggregate + double-GEMM + epilogue ----------------
// One wave owns 16 nodes. INF32: hin is fp32 [N][128]; else bf16-packed [N][64] dwords.
// MODE 0: leaky_relu -> bf16 out (stride 128). MODE 1: log_softmax -> fp32 out (stride 40).
// Grid exactly 625 blocks x 5 waves = 3125 waves = NN/16; no early returns.
template <int NT, int MODE, int INF32>
__global__ __launch_bounds__(320) void k_fused(
    const void* __restrict__ hin_v,
    const int* __restrict__ offsets, const int* __restrict__ csr,
    const float* __restrict__ inv,
    const unsigned short* __restrict__ B1f, const unsigned short* __restrict__ B2f,
    const float* __restrict__ bias, void* __restrict__ out_v) {
    __shared__ unsigned lds[5][16][72];  // rows 288B apart, 16B-aligned frag reads
    int wid = threadIdx.x >> 6;
    int lane = threadIdx.x & 63;
    int m0 = (blockIdx.x * 5 + wid) * 16;

    // ---- gather + mean-aggregate 16 rows (lane owns dims 2*lane, 2*lane+1) ----
    for (int r = 0; r < 16; ++r) {
        int node = m0 + r;
        int beg = offsets[node], end = offsets[node + 1];
        float a0 = 0.f, a1 = 0.f;
        if (INF32) {
            const float* hf = (const float*)hin_v;
            for (int e = beg; e < end; ++e) {
                int s0 = csr[e];
                float2 v = *(const float2*)(hf + (size_t)s0 * HH + 2 * lane);
                a0 += v.x; a1 += v.y;
            }
        } else {
            const unsigned* hw = (const unsigned*)hin_v;
            int e = beg;
            for (; e + 1 < end; e += 2) {
                unsigned v0 = hw[csr[e] * 64 + lane];
                unsigned v1 = hw[csr[e + 1] * 64 + lane];
                a0 += bflo(v0) + bflo(v1);
                a1 += bfhi(v0) + bfhi(v1);
            }
            if (e < end) {
                unsigned v0 = hw[csr[e] * 64 + lane];
                a0 += bflo(v0);
                a1 += bfhi(v0);
            }
        }
        float sc = inv[node];
        lds[wid][r][lane] = ((unsigned)f2bf(a1 * sc) << 16) | (unsigned)f2bf(a0 * sc);
    }
    __syncthreads();

    // ---- MFMA: A1 from LDS (frag order), A2 from global (self term) ----
    int nin = lane & 15;
    int kq = lane >> 4;
    const unsigned* arow = &lds[wid][nin][0];

    f32x4 acc[NT];
#pragma unroll
    for (int t = 0; t < NT; ++t) acc[t] = (f32x4){0.f, 0.f, 0.f, 0.f};

#pragma unroll
    for (int kt = 0; kt < 4; ++kt) {
        bf16x8 a1 = *(const bf16x8*)(arow + kt * 16 + kq * 4);
        bf16x8 a2;
        if (INF32) {
            const float* hf = (const float*)hin_v;
            const float* rp = hf + (size_t)(m0 + nin) * HH + kt * 32 + kq * 8;
            float4 p0 = *(const float4*)(rp);
            float4 p1 = *(const float4*)(rp + 4);
            a2[0] = (short)f2bf(p0.x); a2[1] = (short)f2bf(p0.y);
            a2[2] = (short)f2bf(p0.z); a2[3] = (short)f2bf(p0.w);
            a2[4] = (short)f2bf(p1.x); a2[5] = (short)f2bf(p1.y);
            a2[6] = (short)f2bf(p1.z); a2[7] = (short)f2bf(p1.w);
        } else {
            const unsigned short* hb = (const unsigned short*)hin_v;
            a2 = *(const bf16x8*)(hb + (size_t)(m0 + nin) * HH + kt * 32 + kq * 8);
        }
#pragma unroll
        for (int t = 0; t < NT; ++t) {
            bf16x8 b1 = *(const bf16x8*)(B1f + (((kt * NT + t) * 64) + lane) * 8);
            acc[t] = __builtin_amdgcn_mfma_f32_16x16x32_bf16(a1, b1, acc[t], 0, 0, 0);
        }
#pragma unroll
        for (int t = 0; t < NT; ++t) {
            bf16x8 b2 = *(const bf16x8*)(B2f + (((kt * NT + t) * 64) + lane) * 8);
            acc[t] = __builtin_amdgcn_mfma_f32_16x16x32_bf16(a2, b2, acc[t], 0, 0, 0);
        }
    }

    // C/D layout: col = lane&15, row = (lane>>4)*4 + reg
    if (MODE == 0) {
        unsigned short* out = (unsigned short*)out_v;
#pragma unroll
        for (int t = 0; t < NT; ++t) {
            int col = t * 16 + nin;
            float bv = bias[col];
#pragma unroll
            for (int r = 0; r < 4; ++r) {
                int m = m0 + kq * 4 + r;
                float v = acc[t][r] + bv;
                v = fmaxf(v, NEG * v);
                out[(size_t)m * HH + col] = f2bf(v);
            }
        }
    } else {
        float* out = (float*)out_v;
        float bv[NT];
#pragma unroll
        for (int t = 0; t < NT; ++t) {
            int col = t * 16 + nin;
            bv[t] = (col < CC) ? bias[col] : 0.f;
        }
#pragma unroll
        for (int r = 0; r < 4; ++r) {
            int m = m0 + kq * 4 + r;
            float v[NT];
            float mx = -1e30f;
#pragma unroll
            for (int t = 0; t < NT; ++t) {
                int col = t * 16 + nin;
                v[t] = acc[t][r] + bv[t];
                if (col < CC) mx = fmaxf(mx, v[t]);
            }
            for (int off = 1; off < 16; off <<= 1) mx = fmaxf(mx, __shfl_xor(mx, off, 64));
            float sm = 0.f;
#pragma unroll
            for (int t = 0; t < NT; ++t) {
                int col = t * 16 + nin;
                if (col < CC) sm += expf(v[t] - mx);
            }
            for (int off = 1; off < 16; off <<= 1) sm += __shfl_xor(sm, off, 64);
            float lse = mx + logf(sm);
#pragma unroll
            for (int t = 0; t < NT; ++t) {
                int col = t * 16 + nin;
                if (col < CC) out[(size_t)m * CC + col] = v[t] - lse;
            }
        }
    }
}

extern "C" void kernel_launch(void* const* d_in, const int* in_sizes, int n_in,
                              void* d_out, int out_size, void* d_ws, size_t ws_size,
                              hipStream_t stream) {
    const float* x      = (const float*)d_in[0];   // fp32 N x 128
    const int*   ei     = (const int*)d_in[1];     // [2, E] int32
    const float* enc_Wl = (const float*)d_in[2];
    const float* enc_Wr = (const float*)d_in[3];
    const float* enc_b  = (const float*)d_in[4];
    const float* lay_Wl = (const float*)d_in[5];   // [2,128,128]
    const float* lay_Wr = (const float*)d_in[6];
    const float* lay_b  = (const float*)d_in[7];   // [2,128]
    const float* dec_Wl = (const float*)d_in[8];   // [128,40]
    const float* dec_Wr = (const float*)d_in[9];
    const float* dec_b  = (const float*)d_in[10];  // [40]
    float* out = (float*)d_out;

    const int* src = ei;
    const int* dst = ei + EE;

    // ---- workspace carve (256B aligned), total ~28.8 MB ----
    char* p = (char*)d_ws;
    auto carve = [&](size_t bytes) {
        char* r = p;
        p += (bytes + 255) & ~(size_t)255;
        return r;
    };
    int*            counts  = (int*)carve(NN * 4);
    int*            offsets = (int*)carve((NN + 1) * 4);
    int*            cursor  = (int*)carve(NN * 4);
    int*            csr     = (int*)carve(EE * 4);
    float*          inv     = (float*)carve(NN * 4);
    unsigned short* h1      = (unsigned short*)carve((size_t)NN * HH * 2);
    unsigned short* h2      = (unsigned short*)carve((size_t)NN * HH * 2);
    unsigned short* wf[8];
    for (int i = 0; i < 6; ++i) wf[i] = (unsigned short*)carve(HH * HH * 2);
    wf[6] = (unsigned short*)carve(HH * 48 * 2);
    wf[7] = (unsigned short*)carve(HH * 48 * 2);

    // ---- weight swizzles (independent of CSR chain) ----
    {
        int blk = (HH * HH + 255) / 256;
        k_swz<<<blk, 256, 0, stream>>>(enc_Wl, wf[0], HH, HH);
        k_swz<<<blk, 256, 0, stream>>>(enc_Wr, wf[1], HH, HH);
        k_swz<<<blk, 256, 0, stream>>>(lay_Wl, wf[2], HH, HH);
        k_swz<<<blk, 256, 0, stream>>>(lay_Wr, wf[3], HH, HH);
        k_swz<<<blk, 256, 0, stream>>>(lay_Wl + HH * HH, wf[4], HH, HH);
        k_swz<<<blk, 256, 0, stream>>>(lay_Wr + HH * HH, wf[5], HH, HH);
        int blk2 = (HH * 48 + 255) / 256;
        k_swz<<<blk2, 256, 0, stream>>>(dec_Wl, wf[6], CC, 48);
        k_swz<<<blk2, 256, 0, stream>>>(dec_Wr, wf[7], CC, 48);
    }

    // ---- CSR build ----
    hipMemsetAsync(counts, 0, NN * 4, stream);
    int eblk = (EE + 255) / 256;
    k_count<<<eblk, 256, 0, stream>>>(dst, counts);
    k_scan2<<<1, 1024, 0, stream>>>(counts, offsets, cursor, inv);
    k_scatter<<<eblk, 256, 0, stream>>>(src, dst, cursor, csr);

    // ---- fused layer pipeline: 625 blocks x 5 waves = NN/16 waves ----
    const int FB = 625;
    k_fused<8, 0, 1><<<FB, 320, 0, stream>>>(x,  offsets, csr, inv, wf[0], wf[1], enc_b,      h1);
    k_fused<8, 0, 0><<<FB, 320, 0, stream>>>(h1, offsets, csr, inv, wf[2], wf[3], lay_b,      h2);
    k_fused<8, 0, 0><<<FB, 320, 0, stream>>>(h2, offsets, csr, inv, wf[4], wf[5], lay_b + HH, h1);
    k_fused<3, 1, 0><<<FB, 320, 0, stream>>>(h1, offsets, csr, inv, wf[6], wf[7], dec_b,      out);
}

// Round 4
// 495.304 us; speedup vs baseline: 1.4172x; 1.4172x over previous
//
#include <hip/hip_runtime.h>
#include <hip/hip_bf16.h>

#define NN 50000
#define EE 600000
#define HH 128
#define CC 40
#define NEG 0.1f

typedef __attribute__((ext_vector_type(8))) short bf16x8;
typedef __attribute__((ext_vector_type(4))) float f32x4;

__device__ __forceinline__ unsigned short f2bf(float f) {
    unsigned u = __float_as_uint(f);
    unsigned r = u + 0x7fffu + ((u >> 16) & 1u);
    return (unsigned short)(r >> 16);
}
__device__ __forceinline__ float bfhi(unsigned v) { return __uint_as_float(v & 0xFFFF0000u); }
__device__ __forceinline__ float bflo(unsigned v) { return __uint_as_float(v << 16); }

// ---------------- CSR build ----------------

__global__ void k_count(const int* __restrict__ dst, int* __restrict__ counts) {
    int e = blockIdx.x * blockDim.x + threadIdx.x;
    if (e < EE) {
        int d = dst[e];
        if ((unsigned)d < (unsigned)NN) atomicAdd(&counts[d], 1);
    }
}

// simple 3-phase single-block scan: 1024 threads, chunk = 49 (1024*49 >= NN)
__global__ void k_scan2(const int* __restrict__ counts, int* __restrict__ offsets,
                        int* __restrict__ cursor, float* __restrict__ inv) {
    __shared__ int part[1024];
    __shared__ int wtot[16];
    __shared__ int wex[16];
    const int CH = 49;
    int t = threadIdx.x;
    int lo = t * CH;
    int hi = lo + CH; if (hi > NN) hi = NN;
    int s = 0;
    for (int i = lo; i < hi; ++i) s += counts[i];
    part[t] = s;
    __syncthreads();
    if (t < 16) {
        int run = 0;
        for (int j = 0; j < 64; ++j) {
            int v = part[t * 64 + j];
            part[t * 64 + j] = run;
            run += v;
        }
        wtot[t] = run;
    }
    __syncthreads();
    if (t == 0) {
        int run = 0;
        for (int w = 0; w < 16; ++w) { wex[w] = run; run += wtot[w]; }
        offsets[NN] = run;
    }
    __syncthreads();
    int run = wex[t >> 6] + part[t];
    for (int i = lo; i < hi; ++i) {
        int c = counts[i];
        offsets[i] = run;
        cursor[i]  = run;
        inv[i] = (c > 0) ? 1.0f / (float)c : 1.0f;
        run += c;
    }
}

__global__ void k_scatter(const int* __restrict__ src, const int* __restrict__ dst,
                          int* __restrict__ cursor, int* __restrict__ csr) {
    int e = blockIdx.x * blockDim.x + threadIdx.x;
    if (e < EE) {
        int d = dst[e];
        if ((unsigned)d < (unsigned)NN) {
            int pos = atomicAdd(&cursor[d], 1);
            csr[pos] = src[e];
        }
    }
}

// ---------------- weight swizzle (fp32 -> bf16 B-fragment order) ----------------
// B-frag for 16x16x32: lane l holds B[k = kt*32 + (l>>4)*8 + j][n = tile*16 + (l&15)]
__global__ void k_swz(const float* __restrict__ W, unsigned short* __restrict__ dstf,
                      int dout, int doutp) {
    int idx = blockIdx.x * blockDim.x + threadIdx.x;
    int tot = HH * doutp;
    if (idx >= tot) return;
    int k = idx / doutp, n = idx % doutp;
    unsigned short val = (n < dout) ? f2bf(W[k * dout + n]) : (unsigned short)0;
    int kt = k >> 5, kin = k & 31, nt = n >> 4, nin = n & 15;
    int lane = ((kin >> 3) << 4) | nin;
    int j = kin & 7;
    int NT = doutp >> 4;
    dstf[(((kt * NT + nt) * 64) + lane) * 8 + j] = val;
}

// ---------------- fused aggregate + double-GEMM + epilogue ----------------
// Block = 256 threads = 4 waves, owns 16 nodes. Gather: wave owns 4 nodes
// (4-deep edge unroll). GEMM: MODE 0 -> each wave computes 2 of the 8 column
// tiles; MODE 1 -> wave 0 computes all 3 tiles + log_softmax (others exit
// after the barrier). Grid exactly NN/16 = 3125 blocks.
template <int NT, int MODE, int INF32>
__global__ __launch_bounds__(256) void k_fused(
    const void* __restrict__ hin_v,
    const int* __restrict__ offsets, const int* __restrict__ csr,
    const float* __restrict__ inv,
    const unsigned short* __restrict__ B1f, const unsigned short* __restrict__ B2f,
    const float* __restrict__ bias, void* __restrict__ out_v) {
    __shared__ unsigned lds[16][72];   // rows 288B apart, 16B-aligned frag reads
    int wid = threadIdx.x >> 6;        // 0..3
    int lane = threadIdx.x & 63;
    int m0 = blockIdx.x * 16;

    // ---- gather + mean-aggregate: wave owns nodes m0+wid*4 .. +3 ----
#pragma unroll
    for (int r = 0; r < 4; ++r) {
        int node = m0 + wid * 4 + r;
        int beg = offsets[node], end = offsets[node + 1];
        float a0 = 0.f, a1 = 0.f;
        int e = beg;
        if (INF32) {
            const float* hf = (const float*)hin_v;
            for (; e + 3 < end; e += 4) {
                int s0 = csr[e], s1 = csr[e + 1], s2 = csr[e + 2], s3 = csr[e + 3];
                float2 v0 = *(const float2*)(hf + s0 * HH + 2 * lane);
                float2 v1 = *(const float2*)(hf + s1 * HH + 2 * lane);
                float2 v2 = *(const float2*)(hf + s2 * HH + 2 * lane);
                float2 v3 = *(const float2*)(hf + s3 * HH + 2 * lane);
                a0 += (v0.x + v1.x) + (v2.x + v3.x);
                a1 += (v0.y + v1.y) + (v2.y + v3.y);
            }
            for (; e < end; ++e) {
                float2 v = *(const float2*)(hf + csr[e] * HH + 2 * lane);
                a0 += v.x; a1 += v.y;
            }
        } else {
            const unsigned* hw = (const unsigned*)hin_v;
            for (; e + 3 < end; e += 4) {
                int s0 = csr[e], s1 = csr[e + 1], s2 = csr[e + 2], s3 = csr[e + 3];
                unsigned v0 = hw[s0 * 64 + lane];
                unsigned v1 = hw[s1 * 64 + lane];
                unsigned v2 = hw[s2 * 64 + lane];
                unsigned v3 = hw[s3 * 64 + lane];
                a0 += (bflo(v0) + bflo(v1)) + (bflo(v2) + bflo(v3));
                a1 += (bfhi(v0) + bfhi(v1)) + (bfhi(v2) + bfhi(v3));
            }
            for (; e < end; ++e) {
                unsigned v = hw[csr[e] * 64 + lane];
                a0 += bflo(v); a1 += bfhi(v);
            }
        }
        float sc = inv[node];
        lds[wid * 4 + r][lane] = ((unsigned)f2bf(a1 * sc) << 16) | (unsigned)f2bf(a0 * sc);
    }
    __syncthreads();

    if (MODE == 1 && wid != 0) return;   // softmax wave only (after barrier)

    // ---- MFMA: A1 from LDS (frag order), A2 from global (self term) ----
    int nin = lane & 15;
    int kq = lane >> 4;
    const unsigned* arow = &lds[nin][0];
    constexpr int TW = (MODE == 0) ? 2 : NT;

    f32x4 acc[TW];
#pragma unroll
    for (int j = 0; j < TW; ++j) acc[j] = (f32x4){0.f, 0.f, 0.f, 0.f};

#pragma unroll
    for (int kt = 0; kt < 4; ++kt) {
        bf16x8 a1 = *(const bf16x8*)(arow + kt * 16 + kq * 4);
        bf16x8 a2;
        if (INF32) {
            const float* hf = (const float*)hin_v;
            const float* rp = hf + (m0 + nin) * HH + kt * 32 + kq * 8;
            float4 p0 = *(const float4*)(rp);
            float4 p1 = *(const float4*)(rp + 4);
            a2[0] = (short)f2bf(p0.x); a2[1] = (short)f2bf(p0.y);
            a2[2] = (short)f2bf(p0.z); a2[3] = (short)f2bf(p0.w);
            a2[4] = (short)f2bf(p1.x); a2[5] = (short)f2bf(p1.y);
            a2[6] = (short)f2bf(p1.z); a2[7] = (short)f2bf(p1.w);
        } else {
            const unsigned short* hb = (const unsigned short*)hin_v;
            a2 = *(const bf16x8*)(hb + (m0 + nin) * HH + kt * 32 + kq * 8);
        }
#pragma unroll
        for (int j = 0; j < TW; ++j) {
            int tile = (MODE == 0) ? (wid * 2 + j) : j;
            bf16x8 b1 = *(const bf16x8*)(B1f + (((kt * NT + tile) * 64) + lane) * 8);
            acc[j] = __builtin_amdgcn_mfma_f32_16x16x32_bf16(a1, b1, acc[j], 0, 0, 0);
        }
#pragma unroll
        for (int j = 0; j < TW; ++j) {
            int tile = (MODE == 0) ? (wid * 2 + j) : j;
            bf16x8 b2 = *(const bf16x8*)(B2f + (((kt * NT + tile) * 64) + lane) * 8);
            acc[j] = __builtin_amdgcn_mfma_f32_16x16x32_bf16(a2, b2, acc[j], 0, 0, 0);
        }
    }

    // C/D layout: col = lane&15, row = (lane>>4)*4 + reg
    if (MODE == 0) {
        unsigned short* out = (unsigned short*)out_v;
#pragma unroll
        for (int j = 0; j < TW; ++j) {
            int col = (wid * 2 + j) * 16 + nin;
            float bv = bias[col];
#pragma unroll
            for (int r = 0; r < 4; ++r) {
                int m = m0 + kq * 4 + r;
                float v = acc[j][r] + bv;
                v = fmaxf(v, NEG * v);
                out[m * HH + col] = f2bf(v);
            }
        }
    } else {
        float* out = (float*)out_v;
        float bv[NT];
#pragma unroll
        for (int t = 0; t < NT; ++t) {
            int col = t * 16 + nin;
            bv[t] = (col < CC) ? bias[col] : 0.f;
        }
#pragma unroll
        for (int r = 0; r < 4; ++r) {
            int m = m0 + kq * 4 + r;
            float v[NT];
            float mx = -1e30f;
#pragma unroll
            for (int t = 0; t < NT; ++t) {
                int col = t * 16 + nin;
                v[t] = acc[t][r] + bv[t];
                if (col < CC) mx = fmaxf(mx, v[t]);
            }
            for (int off = 1; off < 16; off <<= 1) mx = fmaxf(mx, __shfl_xor(mx, off, 64));
            float sm = 0.f;
#pragma unroll
            for (int t = 0; t < NT; ++t) {
                int col = t * 16 + nin;
                if (col < CC) sm += expf(v[t] - mx);
            }
            for (int off = 1; off < 16; off <<= 1) sm += __shfl_xor(sm, off, 64);
            float lse = mx + logf(sm);
#pragma unroll
            for (int t = 0; t < NT; ++t) {
                int col = t * 16 + nin;
                if (col < CC) out[m * CC + col] = v[t] - lse;
            }
        }
    }
}

extern "C" void kernel_launch(void* const* d_in, const int* in_sizes, int n_in,
                              void* d_out, int out_size, void* d_ws, size_t ws_size,
                              hipStream_t stream) {
    const float* x      = (const float*)d_in[0];   // fp32 N x 128
    const int*   ei     = (const int*)d_in[1];     // [2, E] int32
    const float* enc_Wl = (const float*)d_in[2];
    const float* enc_Wr = (const float*)d_in[3];
    const float* enc_b  = (const float*)d_in[4];
    const float* lay_Wl = (const float*)d_in[5];   // [2,128,128]
    const float* lay_Wr = (const float*)d_in[6];
    const float* lay_b  = (const float*)d_in[7];   // [2,128]
    const float* dec_Wl = (const float*)d_in[8];   // [128,40]
    const float* dec_Wr = (const float*)d_in[9];
    const float* dec_b  = (const float*)d_in[10];  // [40]
    float* out = (float*)d_out;

    const int* src = ei;
    const int* dst = ei + EE;

    // ---- workspace carve (256B aligned), total ~28.8 MB ----
    char* p = (char*)d_ws;
    auto carve = [&](size_t bytes) {
        char* r = p;
        p += (bytes + 255) & ~(size_t)255;
        return r;
    };
    int*            counts  = (int*)carve(NN * 4);
    int*            offsets = (int*)carve((NN + 1) * 4);
    int*            cursor  = (int*)carve(NN * 4);
    int*            csr     = (int*)carve(EE * 4);
    float*          inv     = (float*)carve(NN * 4);
    unsigned short* h1      = (unsigned short*)carve((size_t)NN * HH * 2);
    unsigned short* h2      = (unsigned short*)carve((size_t)NN * HH * 2);
    unsigned short* wf[8];
    for (int i = 0; i < 6; ++i) wf[i] = (unsigned short*)carve(HH * HH * 2);
    wf[6] = (unsigned short*)carve(HH * 48 * 2);
    wf[7] = (unsigned short*)carve(HH * 48 * 2);

    // ---- weight swizzles (independent of CSR chain) ----
    {
        int blk = (HH * HH + 255) / 256;
        k_swz<<<blk, 256, 0, stream>>>(enc_Wl, wf[0], HH, HH);
        k_swz<<<blk, 256, 0, stream>>>(enc_Wr, wf[1], HH, HH);
        k_swz<<<blk, 256, 0, stream>>>(lay_Wl, wf[2], HH, HH);
        k_swz<<<blk, 256, 0, stream>>>(lay_Wr, wf[3], HH, HH);
        k_swz<<<blk, 256, 0, stream>>>(lay_Wl + HH * HH, wf[4], HH, HH);
        k_swz<<<blk, 256, 0, stream>>>(lay_Wr + HH * HH, wf[5], HH, HH);
        int blk2 = (HH * 48 + 255) / 256;
        k_swz<<<blk2, 256, 0, stream>>>(dec_Wl, wf[6], CC, 48);
        k_swz<<<blk2, 256, 0, stream>>>(dec_Wr, wf[7], CC, 48);
    }

    // ---- CSR build ----
    hipMemsetAsync(counts, 0, NN * 4, stream);
    int eblk = (EE + 255) / 256;
    k_count<<<eblk, 256, 0, stream>>>(dst, counts);
    k_scan2<<<1, 1024, 0, stream>>>(counts, offsets, cursor, inv);
    k_scatter<<<eblk, 256, 0, stream>>>(src, dst, cursor, csr);

    // ---- fused layer pipeline: 3125 blocks x 4 waves = 12500 waves ----
    const int FB = NN / 16;   // 3125
    k_fused<8, 0, 1><<<FB, 256, 0, stream>>>(x,  offsets, csr, inv, wf[0], wf[1], enc_b,      h1);
    k_fused<8, 0, 0><<<FB, 256, 0, stream>>>(h1, offsets, csr, inv, wf[2], wf[3], lay_b,      h2);
    k_fused<8, 0, 0><<<FB, 256, 0, stream>>>(h2, offsets, csr, inv, wf[4], wf[5], lay_b + HH, h1);
    k_fused<3, 1, 0><<<FB, 256, 0, stream>>>(h1, offsets, csr, inv, wf[6], wf[7], dec_b,      out);
}

// Round 5
// 348.297 us; speedup vs baseline: 2.0153x; 1.4221x over previous
//
#include <hip/hip_runtime.h>
#include <hip/hip_bf16.h>

#define NN 50000
#define EE 600000
#define HH 128
#define CC 40
#define NEG 0.1f
#define SCAN_NB 196   // 196*256 = 50176 >= NN

typedef __attribute__((ext_vector_type(8))) short bf16x8;
typedef __attribute__((ext_vector_type(4))) float f32x4;

__device__ __forceinline__ unsigned short f2bf(float f) {
    unsigned u = __float_as_uint(f);
    unsigned r = u + 0x7fffu + ((u >> 16) & 1u);
    return (unsigned short)(r >> 16);
}
__device__ __forceinline__ float bfhi(unsigned v) { return __uint_as_float(v & 0xFFFF0000u); }
__device__ __forceinline__ float bflo(unsigned v) { return __uint_as_float(v << 16); }

// ---------------- CSR build ----------------

__global__ void k_count(const int* __restrict__ dst, int* __restrict__ counts) {
    int t = blockIdx.x * blockDim.x + threadIdx.x;
    if (t < EE / 4) {
        int4 d = ((const int4*)dst)[t];
        if ((unsigned)d.x < (unsigned)NN) atomicAdd(&counts[d.x], 1);
        if ((unsigned)d.y < (unsigned)NN) atomicAdd(&counts[d.y], 1);
        if ((unsigned)d.z < (unsigned)NN) atomicAdd(&counts[d.z], 1);
        if ((unsigned)d.w < (unsigned)NN) atomicAdd(&counts[d.w], 1);
    }
}

// Phase A: per-block (256-node) totals
__global__ void k_scanA(const int* __restrict__ counts, int* __restrict__ blocksums) {
    int t = threadIdx.x, b = blockIdx.x;
    int i = b * 256 + t;
    int v = (i < NN) ? counts[i] : 0;
    for (int off = 1; off < 64; off <<= 1) v += __shfl_xor(v, off, 64);
    __shared__ int ws[4];
    if ((t & 63) == 0) ws[t >> 6] = v;
    __syncthreads();
    if (t == 0) blocksums[b] = ws[0] + ws[1] + ws[2] + ws[3];
}

// Phase C: block offset from blocksums + in-block exclusive scan -> offsets/cursor/inv
__global__ void k_scanC(const int* __restrict__ counts, const int* __restrict__ blocksums,
                        int* __restrict__ offsets, int* __restrict__ cursor,
                        float* __restrict__ inv) {
    int t = threadIdx.x, b = blockIdx.x, lane = t & 63, w = t >> 6;
    __shared__ int ws1[4];
    __shared__ int ws2[4];
    // block offset = sum_{j<b} blocksums[j]
    int r = (t < SCAN_NB && t < b) ? blocksums[t] : 0;
    for (int off = 1; off < 64; off <<= 1) r += __shfl_xor(r, off, 64);
    if (lane == 0) ws1[w] = r;
    __syncthreads();
    int blockoff = ws1[0] + ws1[1] + ws1[2] + ws1[3];
    // in-block inclusive scan
    int i = b * 256 + t;
    int c = (i < NN) ? counts[i] : 0;
    int v = c;
    for (int off = 1; off < 64; off <<= 1) {
        int u = __shfl_up(v, off, 64);
        if (lane >= off) v += u;
    }
    if (lane == 63) ws2[w] = v;
    __syncthreads();
    int woff = 0;
    for (int j = 0; j < w; ++j) woff += ws2[j];
    int excl = blockoff + woff + (v - c);
    if (i < NN) {
        offsets[i] = excl;
        cursor[i]  = excl;
        inv[i] = (c > 0) ? 1.0f / (float)c : 1.0f;
    }
    if (b == SCAN_NB - 1 && t == 0) offsets[NN] = blockoff + blocksums[SCAN_NB - 1];
}

__global__ void k_scatter(const int* __restrict__ src, const int* __restrict__ dst,
                          int* __restrict__ cursor, int* __restrict__ csr) {
    int t = blockIdx.x * blockDim.x + threadIdx.x;
    if (t < EE / 4) {
        int4 s = ((const int4*)src)[t];
        int4 d = ((const int4*)dst)[t];
        if ((unsigned)d.x < (unsigned)NN) csr[atomicAdd(&cursor[d.x], 1)] = s.x;
        if ((unsigned)d.y < (unsigned)NN) csr[atomicAdd(&cursor[d.y], 1)] = s.y;
        if ((unsigned)d.z < (unsigned)NN) csr[atomicAdd(&cursor[d.z], 1)] = s.z;
        if ((unsigned)d.w < (unsigned)NN) csr[atomicAdd(&cursor[d.w], 1)] = s.w;
    }
}

// ---------------- fused weight swizzle (fp32 -> bf16 B-fragment order) ----------------
// B-frag for 16x16x32: lane l holds B[k = kt*32 + (l>>4)*8 + j][n = tile*16 + (l&15)]
struct SwzArgs {
    const float* src[8];
    unsigned short* dst[8];
};

template <int DOUT, int DOUTP>
__device__ __forceinline__ void swz_one(const float* __restrict__ W,
                                        unsigned short* __restrict__ dstf, int idx) {
    int k = idx / DOUTP, n = idx % DOUTP;
    unsigned short val = (n < DOUT) ? f2bf(W[k * DOUT + n]) : (unsigned short)0;
    int kt = k >> 5, kin = k & 31, nt = n >> 4, nin = n & 15;
    int lane = ((kin >> 3) << 4) | nin;
    int j = kin & 7;
    int NT = DOUTP >> 4;
    dstf[(((kt * NT + nt) * 64) + lane) * 8 + j] = val;
}

// blocks 0..383: six 128x128 weights (64 blocks each); 384..431: two 128x40->48 (24 each)
__global__ void k_swz_all(SwzArgs a) {
    int b = blockIdx.x;
    if (b < 384) {
        int which = b >> 6;
        int idx = (b & 63) * 256 + threadIdx.x;
        swz_one<HH, HH>(a.src[which], a.dst[which], idx);
    } else {
        int bb = b - 384;
        int which = 6 + bb / 24;
        int idx = (bb % 24) * 256 + threadIdx.x;
        swz_one<CC, 48>(a.src[which], a.dst[which], idx);
    }
}

// ---------------- fused aggregate + double-GEMM + epilogue ----------------
// Block = 256 threads = 4 waves, owns 16 nodes. Gather: wave owns 4 nodes
// (4-deep edge unroll). GEMM: MODE 0 -> each wave computes 2 of the 8 column
// tiles; MODE 1 -> wave 0 computes all 3 tiles + log_softmax.
template <int NT, int MODE, int INF32>
__global__ __launch_bounds__(256) void k_fused(
    const void* __restrict__ hin_v,
    const int* __restrict__ offsets, const int* __restrict__ csr,
    const float* __restrict__ inv,
    const unsigned short* __restrict__ B1f, const unsigned short* __restrict__ B2f,
    const float* __restrict__ bias, void* __restrict__ out_v) {
    __shared__ unsigned lds[16][72];   // rows 288B apart, 16B-aligned frag reads
    int wid = threadIdx.x >> 6;        // 0..3
    int lane = threadIdx.x & 63;
    int m0 = blockIdx.x * 16;

    // ---- gather + mean-aggregate: wave owns nodes m0+wid*4 .. +3 ----
#pragma unroll
    for (int r = 0; r < 4; ++r) {
        int node = m0 + wid * 4 + r;
        int beg = offsets[node], end = offsets[node + 1];
        float a0 = 0.f, a1 = 0.f;
        int e = beg;
        if (INF32) {
            const float* hf = (const float*)hin_v;
            for (; e + 3 < end; e += 4) {
                int s0 = csr[e], s1 = csr[e + 1], s2 = csr[e + 2], s3 = csr[e + 3];
                float2 v0 = *(const float2*)(hf + s0 * HH + 2 * lane);
                float2 v1 = *(const float2*)(hf + s1 * HH + 2 * lane);
                float2 v2 = *(const float2*)(hf + s2 * HH + 2 * lane);
                float2 v3 = *(const float2*)(hf + s3 * HH + 2 * lane);
                a0 += (v0.x + v1.x) + (v2.x + v3.x);
                a1 += (v0.y + v1.y) + (v2.y + v3.y);
            }
            for (; e < end; ++e) {
                float2 v = *(const float2*)(hf + csr[e] * HH + 2 * lane);
                a0 += v.x; a1 += v.y;
            }
        } else {
            const unsigned* hw = (const unsigned*)hin_v;
            for (; e + 3 < end; e += 4) {
                int s0 = csr[e], s1 = csr[e + 1], s2 = csr[e + 2], s3 = csr[e + 3];
                unsigned v0 = hw[s0 * 64 + lane];
                unsigned v1 = hw[s1 * 64 + lane];
                unsigned v2 = hw[s2 * 64 + lane];
                unsigned v3 = hw[s3 * 64 + lane];
                a0 += (bflo(v0) + bflo(v1)) + (bflo(v2) + bflo(v3));
                a1 += (bfhi(v0) + bfhi(v1)) + (bfhi(v2) + bfhi(v3));
            }
            for (; e < end; ++e) {
                unsigned v = hw[csr[e] * 64 + lane];
                a0 += bflo(v); a1 += bfhi(v);
            }
        }
        float sc = inv[node];
        lds[wid * 4 + r][lane] = ((unsigned)f2bf(a1 * sc) << 16) | (unsigned)f2bf(a0 * sc);
    }
    __syncthreads();

    if (MODE == 1 && wid != 0) return;   // softmax wave only (after barrier)

    // ---- MFMA: A1 from LDS (frag order), A2 from global (self term) ----
    int nin = lane & 15;
    int kq = lane >> 4;
    const unsigned* arow = &lds[nin][0];
    constexpr int TW = (MODE == 0) ? 2 : NT;

    f32x4 acc[TW];
#pragma unroll
    for (int j = 0; j < TW; ++j) acc[j] = (f32x4){0.f, 0.f, 0.f, 0.f};

#pragma unroll
    for (int kt = 0; kt < 4; ++kt) {
        bf16x8 a1 = *(const bf16x8*)(arow + kt * 16 + kq * 4);
        bf16x8 a2;
        if (INF32) {
            const float* hf = (const float*)hin_v;
            const float* rp = hf + (m0 + nin) * HH + kt * 32 + kq * 8;
            float4 p0 = *(const float4*)(rp);
            float4 p1 = *(const float4*)(rp + 4);
            a2[0] = (short)f2bf(p0.x); a2[1] = (short)f2bf(p0.y);
            a2[2] = (short)f2bf(p0.z); a2[3] = (short)f2bf(p0.w);
            a2[4] = (short)f2bf(p1.x); a2[5] = (short)f2bf(p1.y);
            a2[6] = (short)f2bf(p1.z); a2[7] = (short)f2bf(p1.w);
        } else {
            const unsigned short* hb = (const unsigned short*)hin_v;
            a2 = *(const bf16x8*)(hb + (m0 + nin) * HH + kt * 32 + kq * 8);
        }
#pragma unroll
        for (int j = 0; j < TW; ++j) {
            int tile = (MODE == 0) ? (wid * 2 + j) : j;
            bf16x8 b1 = *(const bf16x8*)(B1f + (((kt * NT + tile) * 64) + lane) * 8);
            acc[j] = __builtin_amdgcn_mfma_f32_16x16x32_bf16(a1, b1, acc[j], 0, 0, 0);
        }
#pragma unroll
        for (int j = 0; j < TW; ++j) {
            int tile = (MODE == 0) ? (wid * 2 + j) : j;
            bf16x8 b2 = *(const bf16x8*)(B2f + (((kt * NT + tile) * 64) + lane) * 8);
            acc[j] = __builtin_amdgcn_mfma_f32_16x16x32_bf16(a2, b2, acc[j], 0, 0, 0);
        }
    }

    // C/D layout: col = lane&15, row = (lane>>4)*4 + reg
    if (MODE == 0) {
        unsigned short* out = (unsigned short*)out_v;
#pragma unroll
        for (int j = 0; j < TW; ++j) {
            int col = (wid * 2 + j) * 16 + nin;
            float bv = bias[col];
#pragma unroll
            for (int r = 0; r < 4; ++r) {
                int m = m0 + kq * 4 + r;
                float v = acc[j][r] + bv;
                v = fmaxf(v, NEG * v);
                out[m * HH + col] = f2bf(v);
            }
        }
    } else {
        float* out = (float*)out_v;
        float bv[NT];
#pragma unroll
        for (int t = 0; t < NT; ++t) {
            int col = t * 16 + nin;
            bv[t] = (col < CC) ? bias[col] : 0.f;
        }
#pragma unroll
        for (int r = 0; r < 4; ++r) {
            int m = m0 + kq * 4 + r;
            float v[NT];
            float mx = -1e30f;
#pragma unroll
            for (int t = 0; t < NT; ++t) {
                int col = t * 16 + nin;
                v[t] = acc[t][r] + bv[t];
                if (col < CC) mx = fmaxf(mx, v[t]);
            }
            for (int off = 1; off < 16; off <<= 1) mx = fmaxf(mx, __shfl_xor(mx, off, 64));
            float sm = 0.f;
#pragma unroll
            for (int t = 0; t < NT; ++t) {
                int col = t * 16 + nin;
                if (col < CC) sm += expf(v[t] - mx);
            }
            for (int off = 1; off < 16; off <<= 1) sm += __shfl_xor(sm, off, 64);
            float lse = mx + logf(sm);
#pragma unroll
            for (int t = 0; t < NT; ++t) {
                int col = t * 16 + nin;
                if (col < CC) out[m * CC + col] = v[t] - lse;
            }
        }
    }
}

extern "C" void kernel_launch(void* const* d_in, const int* in_sizes, int n_in,
                              void* d_out, int out_size, void* d_ws, size_t ws_size,
                              hipStream_t stream) {
    const float* x      = (const float*)d_in[0];   // fp32 N x 128
    const int*   ei     = (const int*)d_in[1];     // [2, E] int32
    const float* enc_Wl = (const float*)d_in[2];
    const float* enc_Wr = (const float*)d_in[3];
    const float* enc_b  = (const float*)d_in[4];
    const float* lay_Wl = (const float*)d_in[5];   // [2,128,128]
    const float* lay_Wr = (const float*)d_in[6];
    const float* lay_b  = (const float*)d_in[7];   // [2,128]
    const float* dec_Wl = (const float*)d_in[8];   // [128,40]
    const float* dec_Wr = (const float*)d_in[9];
    const float* dec_b  = (const float*)d_in[10];  // [40]
    float* out = (float*)d_out;

    const int* src = ei;
    const int* dst = ei + EE;

    // ---- workspace carve (256B aligned), total ~28.8 MB ----
    char* p = (char*)d_ws;
    auto carve = [&](size_t bytes) {
        char* r = p;
        p += (bytes + 255) & ~(size_t)255;
        return r;
    };
    int*            counts    = (int*)carve(NN * 4);
    int*            offsets   = (int*)carve((NN + 1) * 4);
    int*            cursor    = (int*)carve(NN * 4);
    int*            csr       = (int*)carve(EE * 4);
    float*          inv       = (float*)carve(NN * 4);
    int*            blocksums = (int*)carve(SCAN_NB * 4);
    unsigned short* h1        = (unsigned short*)carve((size_t)NN * HH * 2);
    unsigned short* h2        = (unsigned short*)carve((size_t)NN * HH * 2);
    unsigned short* wf[8];
    for (int i = 0; i < 6; ++i) wf[i] = (unsigned short*)carve(HH * HH * 2);
    wf[6] = (unsigned short*)carve(HH * 48 * 2);
    wf[7] = (unsigned short*)carve(HH * 48 * 2);

    // ---- fused weight swizzle (one launch) ----
    {
        SwzArgs a;
        a.src[0] = enc_Wl; a.src[1] = enc_Wr;
        a.src[2] = lay_Wl; a.src[3] = lay_Wr;
        a.src[4] = lay_Wl + HH * HH; a.src[5] = lay_Wr + HH * HH;
        a.src[6] = dec_Wl; a.src[7] = dec_Wr;
        for (int i = 0; i < 8; ++i) a.dst[i] = wf[i];
        k_swz_all<<<432, 256, 0, stream>>>(a);
    }

    // ---- CSR build ----
    hipMemsetAsync(counts, 0, NN * 4, stream);
    int eblk4 = (EE / 4 + 255) / 256;
    k_count<<<eblk4, 256, 0, stream>>>(dst, counts);
    k_scanA<<<SCAN_NB, 256, 0, stream>>>(counts, blocksums);
    k_scanC<<<SCAN_NB, 256, 0, stream>>>(counts, blocksums, offsets, cursor, inv);
    k_scatter<<<eblk4, 256, 0, stream>>>(src, dst, cursor, csr);

    // ---- fused layer pipeline: 3125 blocks x 4 waves ----
    const int FB = NN / 16;   // 3125
    k_fused<8, 0, 1><<<FB, 256, 0, stream>>>(x,  offsets, csr, inv, wf[0], wf[1], enc_b,      h1);
    k_fused<8, 0, 0><<<FB, 256, 0, stream>>>(h1, offsets, csr, inv, wf[2], wf[3], lay_b,      h2);
    k_fused<8, 0, 0><<<FB, 256, 0, stream>>>(h2, offsets, csr, inv, wf[4], wf[5], lay_b + HH, h1);
    k_fused<3, 1, 0><<<FB, 256, 0, stream>>>(h1, offsets, csr, inv, wf[6], wf[7], dec_b,      out);
}

// Round 6
// 339.483 us; speedup vs baseline: 2.0677x; 1.0260x over previous
//
#include <hip/hip_runtime.h>
#include <hip/hip_bf16.h>

#define NN 50000
#define EE 600000
#define HH 128
#define CC 40
#define NEG 0.1f
#define SCAN_NB 196   // 196*256 = 50176 >= NN

typedef __attribute__((ext_vector_type(8))) short bf16x8;
typedef __attribute__((ext_vector_type(4))) float f32x4;

__device__ __forceinline__ unsigned short f2bf(float f) {
    unsigned u = __float_as_uint(f);
    unsigned r = u + 0x7fffu + ((u >> 16) & 1u);
    return (unsigned short)(r >> 16);
}
__device__ __forceinline__ float bfhi(unsigned v) { return __uint_as_float(v & 0xFFFF0000u); }
__device__ __forceinline__ float bflo(unsigned v) { return __uint_as_float(v << 16); }

// ---------------- CSR build ----------------

__global__ void k_count(const int* __restrict__ dst, int* __restrict__ counts) {
    int t = blockIdx.x * blockDim.x + threadIdx.x;
    if (t < EE / 4) {
        int4 d = ((const int4*)dst)[t];
        if ((unsigned)d.x < (unsigned)NN) atomicAdd(&counts[d.x], 1);
        if ((unsigned)d.y < (unsigned)NN) atomicAdd(&counts[d.y], 1);
        if ((unsigned)d.z < (unsigned)NN) atomicAdd(&counts[d.z], 1);
        if ((unsigned)d.w < (unsigned)NN) atomicAdd(&counts[d.w], 1);
    }
}

// Phase A: per-block (256-node) totals
__global__ void k_scanA(const int* __restrict__ counts, int* __restrict__ blocksums) {
    int t = threadIdx.x, b = blockIdx.x;
    int i = b * 256 + t;
    int v = (i < NN) ? counts[i] : 0;
    for (int off = 1; off < 64; off <<= 1) v += __shfl_xor(v, off, 64);
    __shared__ int ws[4];
    if ((t & 63) == 0) ws[t >> 6] = v;
    __syncthreads();
    if (t == 0) blocksums[b] = ws[0] + ws[1] + ws[2] + ws[3];
}

// Phase C: block offset from blocksums + in-block exclusive scan -> offsets/cursor/inv
__global__ void k_scanC(const int* __restrict__ counts, const int* __restrict__ blocksums,
                        int* __restrict__ offsets, int* __restrict__ cursor,
                        float* __restrict__ inv) {
    int t = threadIdx.x, b = blockIdx.x, lane = t & 63, w = t >> 6;
    __shared__ int ws1[4];
    __shared__ int ws2[4];
    int r = (t < SCAN_NB && t < b) ? blocksums[t] : 0;
    for (int off = 1; off < 64; off <<= 1) r += __shfl_xor(r, off, 64);
    if (lane == 0) ws1[w] = r;
    __syncthreads();
    int blockoff = ws1[0] + ws1[1] + ws1[2] + ws1[3];
    int i = b * 256 + t;
    int c = (i < NN) ? counts[i] : 0;
    int v = c;
    for (int off = 1; off < 64; off <<= 1) {
        int u = __shfl_up(v, off, 64);
        if (lane >= off) v += u;
    }
    if (lane == 63) ws2[w] = v;
    __syncthreads();
    int woff = 0;
    for (int j = 0; j < w; ++j) woff += ws2[j];
    int excl = blockoff + woff + (v - c);
    if (i < NN) {
        offsets[i] = excl;
        cursor[i]  = excl;
        inv[i] = (c > 0) ? 1.0f / (float)c : 1.0f;
    }
    if (b == SCAN_NB - 1 && t == 0) offsets[NN] = blockoff + blocksums[SCAN_NB - 1];
}

__global__ void k_scatter(const int* __restrict__ src, const int* __restrict__ dst,
                          int* __restrict__ cursor, int* __restrict__ csr) {
    int t = blockIdx.x * blockDim.x + threadIdx.x;
    if (t < EE / 4) {
        int4 s = ((const int4*)src)[t];
        int4 d = ((const int4*)dst)[t];
        if ((unsigned)d.x < (unsigned)NN) csr[atomicAdd(&cursor[d.x], 1)] = s.x;
        if ((unsigned)d.y < (unsigned)NN) csr[atomicAdd(&cursor[d.y], 1)] = s.y;
        if ((unsigned)d.z < (unsigned)NN) csr[atomicAdd(&cursor[d.z], 1)] = s.z;
        if ((unsigned)d.w < (unsigned)NN) csr[atomicAdd(&cursor[d.w], 1)] = s.w;
    }
}

// ---------------- fused weight swizzle (fp32 -> bf16 B-fragment order) ----------------
// B-frag for 16x16x32: lane l holds B[k = kt*32 + (l>>4)*8 + j][n = tile*16 + (l&15)]
struct SwzArgs {
    const float* src[8];
    unsigned short* dst[8];
};

template <int DOUT, int DOUTP>
__device__ __forceinline__ void swz_one(const float* __restrict__ W,
                                        unsigned short* __restrict__ dstf, int idx) {
    int k = idx / DOUTP, n = idx % DOUTP;
    unsigned short val = (n < DOUT) ? f2bf(W[k * DOUT + n]) : (unsigned short)0;
    int kt = k >> 5, kin = k & 31, nt = n >> 4, nin = n & 15;
    int lane = ((kin >> 3) << 4) | nin;
    int j = kin & 7;
    int NT = DOUTP >> 4;
    dstf[(((kt * NT + nt) * 64) + lane) * 8 + j] = val;
}

// blocks 0..383: six 128x128 weights (64 blocks each); 384..431: two 128x40->48 (24 each)
__global__ void k_swz_all(SwzArgs a) {
    int b = blockIdx.x;
    if (b < 384) {
        int which = b >> 6;
        int idx = (b & 63) * 256 + threadIdx.x;
        swz_one<HH, HH>(a.src[which], a.dst[which], idx);
    } else {
        int bb = b - 384;
        int which = 6 + bb / 24;
        int idx = (bb % 24) * 256 + threadIdx.x;
        swz_one<CC, 48>(a.src[which], a.dst[which], idx);
    }
}

// ---------------- fused aggregate + double-GEMM + epilogue ----------------
// Block = 256 threads = 4 waves, owns 16 nodes (4 per wave).
// Gather: dwordx4 per lane; bf16 row (256B) = 16 lanes, so 4 edge-slots/wave;
// fp32 row (512B) = 32 lanes, 2 edge-slots. The 4 node chains are interleaved
// and software-prefetched one round ahead -> 8 outstanding 16B loads/lane.
// GEMM: MODE 0 -> each wave does 2 of 8 column tiles; MODE 1 -> wave 0 does
// all NT tiles + log_softmax.
template <int NT, int MODE, int INF32>
__global__ __launch_bounds__(256) void k_fused(
    const void* __restrict__ hin_v,
    const int* __restrict__ offsets, const int* __restrict__ csr,
    const float* __restrict__ inv,
    const unsigned short* __restrict__ B1f, const unsigned short* __restrict__ B2f,
    const float* __restrict__ bias, void* __restrict__ out_v) {
    __shared__ unsigned lds[16][72];   // rows 288B apart, 16B-aligned frag reads
    int wid = threadIdx.x >> 6;        // 0..3
    int lane = threadIdx.x & 63;
    int m0 = blockIdx.x * 16;

    int beg[4], end[4];
    int maxd = 0;
#pragma unroll
    for (int n = 0; n < 4; ++n) {
        int node = m0 + wid * 4 + n;
        beg[n] = offsets[node];
        end[n] = offsets[node + 1];
        int d = end[n] - beg[n];
        maxd = maxd > d ? maxd : d;
    }

    if (INF32) {
        // ---- fp32 gather: 32 lanes/row (4 dims/lane), 2 edge-slots ----
        const float4* hf4 = (const float4*)hin_v;
        int g = lane & 31, s = lane >> 5;
        float acc[4][4];
#pragma unroll
        for (int n = 0; n < 4; ++n)
#pragma unroll
            for (int d = 0; d < 4; ++d) acc[n][d] = 0.f;
        int rounds = (maxd + 1) >> 1;

        float4 v[4]; int ok[4];
        auto issue = [&](int r, float4* vv, int* okk) {
#pragma unroll
            for (int n = 0; n < 4; ++n) {
                int idx = beg[n] + r * 2 + s;
                int o = idx < end[n];
                int row = csr[o ? idx : 0];
                vv[n] = hf4[(size_t)row * 32 + g];
                okk[n] = o;
            }
        };
        if (rounds > 0) {
            issue(0, v, ok);
            for (int r = 0; r < rounds; ++r) {
                float4 vn[4]; int okn[4];
                bool more = (r + 1 < rounds);
                if (more) issue(r + 1, vn, okn);
#pragma unroll
                for (int n = 0; n < 4; ++n) {
                    if (ok[n]) {
                        acc[n][0] += v[n].x; acc[n][1] += v[n].y;
                        acc[n][2] += v[n].z; acc[n][3] += v[n].w;
                    }
                }
                if (more) {
#pragma unroll
                    for (int n = 0; n < 4; ++n) { v[n] = vn[n]; ok[n] = okn[n]; }
                }
            }
        }
#pragma unroll
        for (int n = 0; n < 4; ++n) {
#pragma unroll
            for (int d = 0; d < 4; ++d) {
                float t = acc[n][d];
                t += __shfl_xor(t, 32, 64);
                acc[n][d] = t;
            }
            float sc = inv[m0 + wid * 4 + n];
            if (s == 0) {
                unsigned d0 = ((unsigned)f2bf(acc[n][1] * sc) << 16) | f2bf(acc[n][0] * sc);
                unsigned d1 = ((unsigned)f2bf(acc[n][3] * sc) << 16) | f2bf(acc[n][2] * sc);
                uint2 w2; w2.x = d0; w2.y = d1;
                *(uint2*)&lds[wid * 4 + n][2 * g] = w2;
            }
        }
    } else {
        // ---- bf16 gather: 16 lanes/row (8 dims/lane), 4 edge-slots ----
        const uint4* hw4 = (const uint4*)hin_v;
        int g = lane & 15, s = lane >> 4;
        float acc[4][8];
#pragma unroll
        for (int n = 0; n < 4; ++n)
#pragma unroll
            for (int d = 0; d < 8; ++d) acc[n][d] = 0.f;
        int rounds = (maxd + 3) >> 2;

        uint4 v[4]; int ok[4];
        auto issue = [&](int r, uint4* vv, int* okk) {
#pragma unroll
            for (int n = 0; n < 4; ++n) {
                int idx = beg[n] + r * 4 + s;
                int o = idx < end[n];
                int row = csr[o ? idx : 0];
                vv[n] = hw4[(size_t)row * 16 + g];
                okk[n] = o;
            }
        };
        if (rounds > 0) {
            issue(0, v, ok);
            for (int r = 0; r < rounds; ++r) {
                uint4 vn[4]; int okn[4];
                bool more = (r + 1 < rounds);
                if (more) issue(r + 1, vn, okn);
#pragma unroll
                for (int n = 0; n < 4; ++n) {
                    if (ok[n]) {
                        acc[n][0] += bflo(v[n].x); acc[n][1] += bfhi(v[n].x);
                        acc[n][2] += bflo(v[n].y); acc[n][3] += bfhi(v[n].y);
                        acc[n][4] += bflo(v[n].z); acc[n][5] += bfhi(v[n].z);
                        acc[n][6] += bflo(v[n].w); acc[n][7] += bfhi(v[n].w);
                    }
                }
                if (more) {
#pragma unroll
                    for (int n = 0; n < 4; ++n) { v[n] = vn[n]; ok[n] = okn[n]; }
                }
            }
        }
#pragma unroll
        for (int n = 0; n < 4; ++n) {
#pragma unroll
            for (int d = 0; d < 8; ++d) {
                float t = acc[n][d];
                t += __shfl_xor(t, 16, 64);
                t += __shfl_xor(t, 32, 64);
                acc[n][d] = t;
            }
            float sc = inv[m0 + wid * 4 + n];
            if (s == 0) {
                uint4 w4;
                w4.x = ((unsigned)f2bf(acc[n][1] * sc) << 16) | f2bf(acc[n][0] * sc);
                w4.y = ((unsigned)f2bf(acc[n][3] * sc) << 16) | f2bf(acc[n][2] * sc);
                w4.z = ((unsigned)f2bf(acc[n][5] * sc) << 16) | f2bf(acc[n][4] * sc);
                w4.w = ((unsigned)f2bf(acc[n][7] * sc) << 16) | f2bf(acc[n][6] * sc);
                *(uint4*)&lds[wid * 4 + n][4 * g] = w4;
            }
        }
    }
    __syncthreads();

    if (MODE == 1 && wid != 0) return;   // softmax wave only (after barrier)

    // ---- MFMA: A1 from LDS (frag order), A2 from global (self term) ----
    int nin = lane & 15;
    int kq = lane >> 4;
    const unsigned* arow = &lds[nin][0];
    constexpr int TW = (MODE == 0) ? 2 : NT;

    f32x4 acc[TW];
#pragma unroll
    for (int j = 0; j < TW; ++j) acc[j] = (f32x4){0.f, 0.f, 0.f, 0.f};

#pragma unroll
    for (int kt = 0; kt < 4; ++kt) {
        bf16x8 a1 = *(const bf16x8*)(arow + kt * 16 + kq * 4);
        bf16x8 a2;
        if (INF32) {
            const float* hf = (const float*)hin_v;
            const float* rp = hf + (m0 + nin) * HH + kt * 32 + kq * 8;
            float4 p0 = *(const float4*)(rp);
            float4 p1 = *(const float4*)(rp + 4);
            a2[0] = (short)f2bf(p0.x); a2[1] = (short)f2bf(p0.y);
            a2[2] = (short)f2bf(p0.z); a2[3] = (short)f2bf(p0.w);
            a2[4] = (short)f2bf(p1.x); a2[5] = (short)f2bf(p1.y);
            a2[6] = (short)f2bf(p1.z); a2[7] = (short)f2bf(p1.w);
        } else {
            const unsigned short* hb = (const unsigned short*)hin_v;
            a2 = *(const bf16x8*)(hb + (m0 + nin) * HH + kt * 32 + kq * 8);
        }
#pragma unroll
        for (int j = 0; j < TW; ++j) {
            int tile = (MODE == 0) ? (wid * 2 + j) : j;
            bf16x8 b1 = *(const bf16x8*)(B1f + (((kt * NT + tile) * 64) + lane) * 8);
            acc[j] = __builtin_amdgcn_mfma_f32_16x16x32_bf16(a1, b1, acc[j], 0, 0, 0);
        }
#pragma unroll
        for (int j = 0; j < TW; ++j) {
            int tile = (MODE == 0) ? (wid * 2 + j) : j;
            bf16x8 b2 = *(const bf16x8*)(B2f + (((kt * NT + tile) * 64) + lane) * 8);
            acc[j] = __builtin_amdgcn_mfma_f32_16x16x32_bf16(a2, b2, acc[j], 0, 0, 0);
        }
    }

    // C/D layout: col = lane&15, row = (lane>>4)*4 + reg
    if (MODE == 0) {
        unsigned short* out = (unsigned short*)out_v;
#pragma unroll
        for (int j = 0; j < TW; ++j) {
            int col = (wid * 2 + j) * 16 + nin;
            float bv = bias[col];
#pragma unroll
            for (int r = 0; r < 4; ++r) {
                int m = m0 + kq * 4 + r;
                float v = acc[j][r] + bv;
                v = fmaxf(v, NEG * v);
                out[m * HH + col] = f2bf(v);
            }
        }
    } else {
        float* out = (float*)out_v;
        float bv[NT];
#pragma unroll
        for (int t = 0; t < NT; ++t) {
            int col = t * 16 + nin;
            bv[t] = (col < CC) ? bias[col] : 0.f;
        }
#pragma unroll
        for (int r = 0; r < 4; ++r) {
            int m = m0 + kq * 4 + r;
            float v[NT];
            float mx = -1e30f;
#pragma unroll
            for (int t = 0; t < NT; ++t) {
                int col = t * 16 + nin;
                v[t] = acc[t][r] + bv[t];
                if (col < CC) mx = fmaxf(mx, v[t]);
            }
            for (int off = 1; off < 16; off <<= 1) mx = fmaxf(mx, __shfl_xor(mx, off, 64));
            float sm = 0.f;
#pragma unroll
            for (int t = 0; t < NT; ++t) {
                int col = t * 16 + nin;
                if (col < CC) sm += expf(v[t] - mx);
            }
            for (int off = 1; off < 16; off <<= 1) sm += __shfl_xor(sm, off, 64);
            float lse = mx + logf(sm);
#pragma unroll
            for (int t = 0; t < NT; ++t) {
                int col = t * 16 + nin;
                if (col < CC) out[m * CC + col] = v[t] - lse;
            }
        }
    }
}

extern "C" void kernel_launch(void* const* d_in, const int* in_sizes, int n_in,
                              void* d_out, int out_size, void* d_ws, size_t ws_size,
                              hipStream_t stream) {
    const float* x      = (const float*)d_in[0];   // fp32 N x 128
    const int*   ei     = (const int*)d_in[1];     // [2, E] int32
    const float* enc_Wl = (const float*)d_in[2];
    const float* enc_Wr = (const float*)d_in[3];
    const float* enc_b  = (const float*)d_in[4];
    const float* lay_Wl = (const float*)d_in[5];   // [2,128,128]
    const float* lay_Wr = (const float*)d_in[6];
    const float* lay_b  = (const float*)d_in[7];   // [2,128]
    const float* dec_Wl = (const float*)d_in[8];   // [128,40]
    const float* dec_Wr = (const float*)d_in[9];
    const float* dec_b  = (const float*)d_in[10];  // [40]
    float* out = (float*)d_out;

    const int* src = ei;
    const int* dst = ei + EE;

    // ---- workspace carve (256B aligned), total ~28.8 MB ----
    char* p = (char*)d_ws;
    auto carve = [&](size_t bytes) {
        char* r = p;
        p += (bytes + 255) & ~(size_t)255;
        return r;
    };
    int*            counts    = (int*)carve(NN * 4);
    int*            offsets   = (int*)carve((NN + 1) * 4);
    int*            cursor    = (int*)carve(NN * 4);
    int*            csr       = (int*)carve(EE * 4);
    float*          inv       = (float*)carve(NN * 4);
    int*            blocksums = (int*)carve(SCAN_NB * 4);
    unsigned short* h1        = (unsigned short*)carve((size_t)NN * HH * 2);
    unsigned short* h2        = (unsigned short*)carve((size_t)NN * HH * 2);
    unsigned short* wf[8];
    for (int i = 0; i < 6; ++i) wf[i] = (unsigned short*)carve(HH * HH * 2);
    wf[6] = (unsigned short*)carve(HH * 48 * 2);
    wf[7] = (unsigned short*)carve(HH * 48 * 2);

    // ---- fused weight swizzle (one launch) ----
    {
        SwzArgs a;
        a.src[0] = enc_Wl; a.src[1] = enc_Wr;
        a.src[2] = lay_Wl; a.src[3] = lay_Wr;
        a.src[4] = lay_Wl + HH * HH; a.src[5] = lay_Wr + HH * HH;
        a.src[6] = dec_Wl; a.src[7] = dec_Wr;
        for (int i = 0; i < 8; ++i) a.dst[i] = wf[i];
        k_swz_all<<<432, 256, 0, stream>>>(a);
    }

    // ---- CSR build ----
    hipMemsetAsync(counts, 0, NN * 4, stream);
    int eblk4 = (EE / 4 + 255) / 256;
    k_count<<<eblk4, 256, 0, stream>>>(dst, counts);
    k_scanA<<<SCAN_NB, 256, 0, stream>>>(counts, blocksums);
    k_scanC<<<SCAN_NB, 256, 0, stream>>>(counts, blocksums, offsets, cursor, inv);
    k_scatter<<<eblk4, 256, 0, stream>>>(src, dst, cursor, csr);

    // ---- fused layer pipeline: 3125 blocks x 4 waves ----
    const int FB = NN / 16;   // 3125
    k_fused<8, 0, 1><<<FB, 256, 0, stream>>>(x,  offsets, csr, inv, wf[0], wf[1], enc_b,      h1);
    k_fused<8, 0, 0><<<FB, 256, 0, stream>>>(h1, offsets, csr, inv, wf[2], wf[3], lay_b,      h2);
    k_fused<8, 0, 0><<<FB, 256, 0, stream>>>(h2, offsets, csr, inv, wf[4], wf[5], lay_b + HH, h1);
    k_fused<3, 1, 0><<<FB, 256, 0, stream>>>(h1, offsets, csr, inv, wf[6], wf[7], dec_b,      out);
}